// Round 3
// baseline (378.289 us; speedup 1.0000x reference)
//
#include <hip/hip_runtime.h>

// PostNormBoth R2: 512 blocks x 256 threads, 1 batch row per block,
// 2 blocks/CU (independent barrier domains). v replicated across all 16
// MFMA columns -> tanh+LN-partials fused into the GEMM wave epilogue
// (2 barriers/step instead of 3). Sliding-window register memory kept.

#define TT 256

typedef __bf16 bf16x8 __attribute__((ext_vector_type(8)));
typedef float  f32x4  __attribute__((ext_vector_type(4)));

__device__ __forceinline__ float fast_tanh(float x) {
    float e = __expf(2.f * x);
    return 1.f - __fdividef(2.f, e + 1.f);
}

template<int CTRL, int RM>
__device__ __forceinline__ float dpp_add(float v) {
    int t = __builtin_amdgcn_update_dpp(0, __float_as_int(v), CTRL, RM, 0xf, true);
    return v + __int_as_float(t);
}
// full 64-lane sum; valid in lane 63.
__device__ __forceinline__ float wave_sum63(float v) {
    v = dpp_add<0xB1,  0xf>(v);   // quad_perm xor1
    v = dpp_add<0x4E,  0xf>(v);   // quad_perm xor2
    v = dpp_add<0x141, 0xf>(v);   // row_half_mirror
    v = dpp_add<0x140, 0xf>(v);   // row_mirror
    v = dpp_add<0x142, 0xa>(v);   // row_bcast15
    v = dpp_add<0x143, 0xc>(v);   // row_bcast31
    return v;
}

// ---- dynamic LDS layout (bytes), per block (1 row) ----
// s_mem [64][256] f32 :     0 (65536)
// s_x   [256]     f32 : 65536 (1024)
// s_yt  [256]     f32 : 66560 (1024)
// s_v   [256]    bf16 : 67584 (512)
// s_red1[4]       f32 : 68096 (16)
// s_red2[4]       f32 : 68112 (16)
// s_wt  [64][8]   f32 : 68128 (2048)
// s_oacc[10]      f32 : 70176 (40)
#define SMEM_BYTES 70240

__global__ __launch_bounds__(256, 2)
void postnorm_kernel(const float* __restrict__ x,
                     const float* __restrict__ W_embed,
                     const float* __restrict__ b_embed,
                     const float* __restrict__ W_update,
                     const float* __restrict__ b_update,
                     const float* __restrict__ gamma,
                     const float* __restrict__ beta,
                     const float* __restrict__ W_out,
                     const float* __restrict__ b_out,
                     const float* __restrict__ ctx_s,
                     float* __restrict__ out)
{
    extern __shared__ __align__(16) char smem[];
    float*  s_mem  = (float*)(smem);
    float*  s_x    = (float*)(smem + 65536);
    float*  s_yt   = (float*)(smem + 66560);
    __bf16* s_v    = (__bf16*)(smem + 67584);
    float*  s_red1 = (float*)(smem + 68096);
    float*  s_red2 = (float*)(smem + 68112);
    float*  s_wt   = (float*)(smem + 68128);
    float*  s_oacc = (float*)(smem + 70176);

    const int tid  = threadIdx.x;          // 0..255; role i = tid
    const int i    = tid;
    const int wave = tid >> 6;             // 0..3, owns W rows [64w,64w+64)
    const int lane = tid & 63;
    const int bn   = lane & 15;            // MFMA col
    const int quad = lane >> 4;
    const int r    = blockIdx.x;           // batch row

    // ---- init ----
    {   f32x4 z = {0.f, 0.f, 0.f, 0.f};
        f32x4* p = (f32x4*)s_mem;
        #pragma unroll
        for (int k = 0; k < 16; ++k) p[tid + k * 256] = z;
    }
    s_x[tid] = x[r * TT + tid];
    if (tid < 10) s_oacc[tid] = 0.f;

    if (tid < 64) {
        float wv[5]; float ssum = 0.f;
        #pragma unroll
        for (int k = 0; k < 5; ++k) {
            int idx = (tid + k - 2) & 63;
            float d = (float)idx - (float)tid;
            wv[k] = expf(-(d * d) * 0.125f);   // TAU=8
            ssum += wv[k];
        }
        #pragma unroll
        for (int k = 0; k < 5; ++k) s_wt[tid * 8 + k] = wv[k] / ssum;
    }

    const float we  = W_embed[i];
    const float be  = b_embed[i];
    const float gm  = gamma[i];
    const float btt = beta[i];
    const float csv = 1.f / (1.f + expf(-ctx_s[0]));

    // per-lane bias fragment for the bn-selected j-tile (constant over t)
    const f32x4 bu4 = *(const f32x4*)(b_update + wave * 64 + (bn & 3) * 16 + quad * 4);

    // ---- W_update rows [64w..64w+64) -> bf16 A-frags in regs ----
    bf16x8 wfa[4][8];
    #pragma unroll
    for (int mt = 0; mt < 4; ++mt) {
        #pragma unroll
        for (int kt = 0; kt < 8; ++kt) {
            const float* wp = W_update + (wave * 64 + mt * 16 + bn) * 256
                                       + kt * 32 + quad * 8;
            f32x4 a = *(const f32x4*)wp;
            f32x4 b = *(const f32x4*)(wp + 4);
            bf16x8 f;
            f[0] = (__bf16)a[0]; f[1] = (__bf16)a[1];
            f[2] = (__bf16)a[2]; f[3] = (__bf16)a[3];
            f[4] = (__bf16)b[0]; f[5] = (__bf16)b[1];
            f[6] = (__bf16)b[2]; f[7] = (__bf16)b[3];
            wfa[mt][kt] = f;
        }
    }

    __syncthreads();
    {   // v(0): memory==0, h==0 -> v = inp(0); s_x[0] is a broadcast read
        float inp = fast_tanh(s_x[0] * we + be);
        s_v[i] = (__bf16)inp;
    }
    float wt0, wt1, wt2, wt3, wt4;
    {   f32x4 wv = *(const f32x4*)(s_wt);
        wt0 = wv[0]; wt1 = wv[1]; wt2 = wv[2]; wt3 = wv[3]; wt4 = s_wt[4];
    }
    __syncthreads();

    float hn = 0.f;
    float w0 = 0.f, w1 = 0.f, w2 = 0.f, w3 = 0.f, w4 = 0.f;  // slots t-2..t+2
    float* mcol = s_mem + i;                 // column i, stride 256 floats
    const __bf16* vsrc = s_v + quad * 8;     // replicated across bn

    #pragma unroll 1
    for (int t = 0; t < TT; ++t) {
        // --- prefetches for this step's P3 (latency hides under MFMA) ---
        const int tn = (t < TT - 1) ? t + 1 : 0;
        float nf  = mcol[((t + 3) & 63) << 8];          // admit slot value
        f32x4 nw  = *(const f32x4*)(s_wt + (tn & 63) * 8);
        float nw4 = s_wt[(tn & 63) * 8 + 4];
        float xN  = s_x[tn];

        // --- P1: MFMA, 4 independent 8-chains; all 16 cols identical ---
        f32x4 a0 = {0,0,0,0}, a1 = {0,0,0,0}, a2 = {0,0,0,0}, a3 = {0,0,0,0};
        #pragma unroll
        for (int kt = 0; kt < 8; ++kt) {
            bf16x8 bfr = *(const bf16x8*)(vsrc + kt * 32);
            a0 = __builtin_amdgcn_mfma_f32_16x16x32_bf16(wfa[0][kt], bfr, a0, 0, 0, 0);
            a1 = __builtin_amdgcn_mfma_f32_16x16x32_bf16(wfa[1][kt], bfr, a1, 0, 0, 0);
            a2 = __builtin_amdgcn_mfma_f32_16x16x32_bf16(wfa[2][kt], bfr, a2, 0, 0, 0);
            a3 = __builtin_amdgcn_mfma_f32_16x16x32_bf16(wfa[3][kt], bfr, a3, 0, 0, 0);
        }
        // fused epilogue: lane (bn,quad) handles tile bn&3, rows quad*4+r
        f32x4 sel = (bn == 0) ? a0 : (bn == 1) ? a1 : (bn == 2) ? a2 : a3;
        float y0 = fast_tanh(sel[0] + bu4[0]);
        float y1 = fast_tanh(sel[1] + bu4[1]);
        float y2 = fast_tanh(sel[2] + bu4[2]);
        float y3 = fast_tanh(sel[3] + bu4[3]);
        float s1 = (y0 + y1) + (y2 + y3);
        float s2 = ((y0 * y0 + y1 * y1) + (y2 * y2 + y3 * y3));
        const bool act = (bn < 4);
        s1 = act ? s1 : 0.f;
        s2 = act ? s2 : 0.f;
        s1 = wave_sum63(s1);
        s2 = wave_sum63(s2);
        if (lane == 63) { s_red1[wave] = s1; s_red2[wave] = s2; }
        if (act) {
            f32x4 ytv = {y0, y1, y2, y3};
            *(f32x4*)(s_yt + wave * 64 + bn * 16 + quad * 4) = ytv;
        }
        __syncthreads();

        // --- P3: LN finalize + window scatter/gather + v(t+1) ---
        f32x4 r1 = *(const f32x4*)s_red1;
        f32x4 r2 = *(const f32x4*)s_red2;
        float yt = s_yt[i];
        float S1 = (r1[0] + r1[1]) + (r1[2] + r1[3]);
        float S2 = (r2[0] + r2[1]) + (r2[2] + r2[3]);
        float mu   = S1 * (1.f / 256.f);
        float var  = S2 * (1.f / 256.f) - mu * mu;
        float rstd = rsqrtf(var + 1e-5f);
        hn = (yt - mu) * rstd * gm + btt;

        w0 += wt0 * hn; w1 += wt1 * hn; w2 += wt2 * hn;
        w3 += wt3 * hn; w4 += wt4 * hn;

        if (t < TT - 1) {
            mcol[((t - 2) & 63) << 8] = w0;      // retire slot t-2
            w0 = w1; w1 = w2; w2 = w3; w3 = w4; w4 = nf;
            float ctx = ((nw[0] * w0 + nw[1] * w1) + (nw[2] * w2 + nw[3] * w3))
                      + nw4 * w4;
            float inp = fast_tanh(xN * we + be);
            float v = inp + csv * ctx + hn;
            s_v[i] = (__bf16)v;
            wt0 = nw[0]; wt1 = nw[1]; wt2 = nw[2]; wt3 = nw[3]; wt4 = nw4;
        }
        __syncthreads();
    }

    // --- epilogue: out[r, o] = h . W_out[o,:] + b_out[o] ---
    #pragma unroll
    for (int o = 0; o < 10; ++o) {
        float p = wave_sum63(hn * W_out[o * 256 + i]);
        if (lane == 63) atomicAdd(&s_oacc[o], p);
    }
    __syncthreads();
    if (tid < 10) out[r * 10 + tid] = s_oacc[tid] + b_out[tid];
}

extern "C" void kernel_launch(void* const* d_in, const int* in_sizes, int n_in,
                              void* d_out, int out_size, void* d_ws, size_t ws_size,
                              hipStream_t stream) {
    const float* x    = (const float*)d_in[0];
    const float* W_e  = (const float*)d_in[1];
    const float* b_e  = (const float*)d_in[2];
    const float* W_u  = (const float*)d_in[3];
    const float* b_u  = (const float*)d_in[4];
    const float* gmm  = (const float*)d_in[5];
    const float* bta  = (const float*)d_in[6];
    const float* W_o  = (const float*)d_in[7];
    const float* b_o  = (const float*)d_in[8];
    const float* cst  = (const float*)d_in[9];
    float* out = (float*)d_out;

    (void)hipFuncSetAttribute(reinterpret_cast<const void*>(postnorm_kernel),
                              hipFuncAttributeMaxDynamicSharedMemorySize,
                              SMEM_BYTES);

    postnorm_kernel<<<dim3(512), dim3(256), SMEM_BYTES, stream>>>(
        x, W_e, b_e, W_u, b_u, gmm, bta, W_o, b_o, cst, out);
}